// Round 3
// baseline (126.615 us; speedup 1.0000x reference)
//
#include <hip/hip_runtime.h>

// Problem constants (match reference)
#define BB 8
#define CC 128
#define HH 112
#define WW 112
#define TH 56                  // output rows per block; 112/56 = 2 tiles/plane
#define TILES_Y (HH / TH)      // 2
#define XG (WW / 8)            // 14 x-groups of 8 outputs
#define PITCH32 64             // u32 words per xq row (16B-aligned rows)
#define PITCH16 128            // u16 cols per xq row

// LUT depthwise 3x3, stride 1, pad 1:
//   t1 = clip(round(w*1000)), t2 = clip(round(x_pad)), both to [-255,255]
//   out = sum_taps sign(t1,t2)*lut[|t1|,|t2|] / 1000, sign=+1 iff strictly same sign.
//
// R3 structure: per kernel-row r, the 3 taps' signed tables are interleaved as
// float4 trow[r][idx] = (t_r0[idx], t_r1[idx], t_r2[idx], 0), idx = t2+255.
// One ds_read_b128 fetches all 3 taps for a pixel. Each thread computes 8
// consecutive outputs: per row-group, 10 pixels -> 10 b128 gathers (vs 24 b32).
// xq holds quantized indices (u16, pixel gx at col gx+2) so an 8-output group
// reads one aligned uint4 + uint2.
__global__ __launch_bounds__(256)
void approx_dconv_kernel(const float* __restrict__ x,
                         const float* __restrict__ w,
                         const float* __restrict__ lut,
                         float* __restrict__ out) {
    __shared__ float4 trow[3][512];                        // 24576 B
    __shared__ unsigned int xq32[(TH + 2) * PITCH32];      // 14848 B

    const int tid   = threadIdx.x;
    const int blk   = blockIdx.x;
    const int tileY = blk % TILES_Y;
    const int bc    = blk / TILES_Y;
    const int c     = bc % CC;
    const int y0    = tileY * TH;

    // ---- 1) build interleaved signed tables (mirror fill, b128 writes) ----
    {
        const int i = tid;                                 // 0..255 == |t2|
        #pragma unroll
        for (int r = 0; r < 3; ++r) {
            float pos[3], neg[3];
            #pragma unroll
            for (int k = 0; k < 3; ++k) {
                float t1 = rintf(w[c * 9 + r * 3 + k] * 1000.0f);
                t1 = fminf(fmaxf(t1, -255.0f), 255.0f);
                const int  i1 = (int)fabsf(t1);
                const bool sp = (t1 > 0.0f);
                const bool sn = (t1 < 0.0f);
                const float v = lut[i1 * 256 + i];         // coalesced row read
                pos[k] = (sp && i > 0) ? v : -v;           // t2 = +i
                neg[k] = (sn && i > 0) ? v : -v;           // t2 = -i
            }
            trow[r][255 + i] = make_float4(pos[0], pos[1], pos[2], 0.f);
            trow[r][255 - i] = make_float4(neg[0], neg[1], neg[2], 0.f);
        }
    }

    // ---- 2) quantize input tile (+halo) into LDS --------------------------
    // pixel gx -> u16 col gx+2; col 1 / col 114 are the x-halo (idx 255).
    const float* xp = x + (size_t)bc * (HH * WW);
    for (int e = tid; e < (TH + 2) * 28; e += 256) {
        const int ry = e / 28;
        const int k4 = e % 28;
        const int gy = y0 + ry - 1;
        unsigned int p0 = 0x00ff00ffu, p1 = 0x00ff00ffu;   // pad (idx 255)
        if (gy >= 0 && gy < HH) {
            const float4 v = *(const float4*)(xp + gy * WW + 4 * k4);
            const int q0 = (int)fminf(fmaxf(rintf(v.x), -255.f), 255.f) + 255;
            const int q1 = (int)fminf(fmaxf(rintf(v.y), -255.f), 255.f) + 255;
            const int q2 = (int)fminf(fmaxf(rintf(v.z), -255.f), 255.f) + 255;
            const int q3 = (int)fminf(fmaxf(rintf(v.w), -255.f), 255.f) + 255;
            p0 = (unsigned)q0 | ((unsigned)q1 << 16);
            p1 = (unsigned)q2 | ((unsigned)q3 << 16);
        }
        xq32[ry * PITCH32 + 2 * k4 + 1] = p0;              // cols 4k+2,4k+3
        xq32[ry * PITCH32 + 2 * k4 + 2] = p1;              // cols 4k+4,4k+5
    }
    {   // x-halo columns (words 0 and 57 — disjoint from interior words 1..56)
        unsigned short* xq16 = (unsigned short*)xq32;
        for (int rr = tid; rr < TH + 2; rr += 256) {
            xq16[rr * PITCH16 + 1]   = 255;                // gx = -1
            xq16[rr * PITCH16 + 114] = 255;                // gx = 112
        }
    }
    __syncthreads();

    // ---- 3) compute: 8 outputs per thread ---------------------------------
    float* op = out + (size_t)bc * (HH * WW) + y0 * WW;
    for (int e = tid; e < TH * XG; e += 256) {
        const int oy = e / XG;
        const int k  = e % XG;
        float a0 = 0.f, a1 = 0.f, a2 = 0.f, a3 = 0.f;
        float a4 = 0.f, a5 = 0.f, a6 = 0.f, a7 = 0.f;
        #pragma unroll
        for (int r = 0; r < 3; ++r) {
            const unsigned int* q = &xq32[(oy + r) * PITCH32 + 4 * k];
            const uint4 A  = *(const uint4*)q;             // cols 8k .. 8k+7
            const uint2 Bv = *(const uint2*)(q + 4);       // cols 8k+8 .. 8k+11
            const float4* T = trow[r];
            const float4 fm1 = T[A.x >> 16];               // pixel 8k-1
            const float4 f0  = T[A.y & 0xffff];            // pixel 8k
            const float4 f1  = T[A.y >> 16];
            const float4 f2  = T[A.z & 0xffff];
            const float4 f3  = T[A.z >> 16];
            const float4 f4  = T[A.w & 0xffff];
            const float4 f5  = T[A.w >> 16];
            const float4 f6  = T[Bv.x & 0xffff];
            const float4 f7  = T[Bv.x >> 16];
            const float4 f8  = T[Bv.y & 0xffff];           // pixel 8k+8
            a0 += fm1.x + f0.y + f1.z;
            a1 += f0.x  + f1.y + f2.z;
            a2 += f1.x  + f2.y + f3.z;
            a3 += f2.x  + f3.y + f4.z;
            a4 += f3.x  + f4.y + f5.z;
            a5 += f4.x  + f5.y + f6.z;
            a6 += f5.x  + f6.y + f7.z;
            a7 += f6.x  + f7.y + f8.z;
        }
        float4 o0, o1;
        o0.x = a0 * 0.001f; o0.y = a1 * 0.001f;
        o0.z = a2 * 0.001f; o0.w = a3 * 0.001f;
        o1.x = a4 * 0.001f; o1.y = a5 * 0.001f;
        o1.z = a6 * 0.001f; o1.w = a7 * 0.001f;
        float* od = op + oy * WW + 8 * k;
        *(float4*)od       = o0;
        *(float4*)(od + 4) = o1;
    }
}

extern "C" void kernel_launch(void* const* d_in, const int* in_sizes, int n_in,
                              void* d_out, int out_size, void* d_ws, size_t ws_size,
                              hipStream_t stream) {
    const float* x   = (const float*)d_in[0];
    const float* w   = (const float*)d_in[1];
    const float* lut = (const float*)d_in[2];
    float* out = (float*)d_out;
    (void)in_sizes; (void)n_in; (void)out_size; (void)d_ws; (void)ws_size;

    const int grid = BB * CC * TILES_Y;                    // 2048
    approx_dconv_kernel<<<grid, 256, 0, stream>>>(x, w, lut, out);
}

// Round 4
// 119.292 us; speedup vs baseline: 1.0614x; 1.0614x over previous
//
#include <hip/hip_runtime.h>
#include <hip/hip_fp16.h>

// Problem constants (match reference)
#define BB 8
#define CC 128
#define HH 112
#define WW 112
#define RT 16                  // output rows per block
#define TILES_Y (HH / RT)      // 7
#define NTH 224                // 16 rows x 14 col-groups; 1 group of 8 outputs/thread

// LUT depthwise 3x3, stride 1, pad 1:
//   t1 = clip(round(w*1000)), t2 = clip(round(x_pad)), both [-255,255]
//   out = sum_taps sign(t1,t2)*lut[|t1|,|t2|] / 1000  (sign=+1 iff strictly same sign)
//
// R4: minimize LDS bank-words gathered per output (R3 post-mortem: random b128
// gather ~38 cyc vs b32 ~14.6 — cost scales with bank-words touched).
//  - Per kernel row r: P_r[idx] = __half2(tap_k0, tap_k1)  (1 word, 2 taps),
//    S_r[idx] = fp32 tap_k2. 9 taps -> ~6.4 words/output (was 9 in R2, 15 R3).
//  - No xq in LDS: pixels quantized in registers from global (x is L2/L3
//    resident; 1.25x re-read). LDS = tables only (12.3 KB) -> 8 blocks/CU.
__global__ __launch_bounds__(NTH, 8)
void approx_dconv_kernel(const float* __restrict__ x,
                         const float* __restrict__ w,
                         const float* __restrict__ lut,
                         float* __restrict__ out) {
    __shared__ __half2 P[3][512];   // (tap k0, tap k1), idx = t2+255
    __shared__ float   S[3][512];   // tap k2

    const int tid   = threadIdx.x;
    const int blk   = blockIdx.x;
    const int tileY = blk % TILES_Y;
    const int bc    = blk / TILES_Y;
    const int c     = bc % CC;

    // ---- 1) build signed per-tap tables (mirror fill) --------------------
    const float* wc = w + c * 9;
    int  i1[9];
    bool sp[9], sn[9];
    #pragma unroll
    for (int k = 0; k < 9; ++k) {
        float t1 = rintf(wc[k] * 1000.0f);
        t1 = fminf(fmaxf(t1, -255.0f), 255.0f);
        i1[k] = (int)fabsf(t1);
        sp[k] = (t1 > 0.0f);
        sn[k] = (t1 < 0.0f);
    }
    for (int i = tid; i < 256; i += NTH) {       // i == |t2|
        #pragma unroll
        for (int r = 0; r < 3; ++r) {
            const float v0 = lut[i1[r * 3 + 0] * 256 + i];
            const float v1 = lut[i1[r * 3 + 1] * 256 + i];
            const float v2 = lut[i1[r * 3 + 2] * 256 + i];
            const float p0 = (sp[r * 3 + 0] && i > 0) ? v0 : -v0;  // t2 = +i
            const float p1 = (sp[r * 3 + 1] && i > 0) ? v1 : -v1;
            const float p2 = (sp[r * 3 + 2] && i > 0) ? v2 : -v2;
            const float n0 = (sn[r * 3 + 0] && i > 0) ? v0 : -v0;  // t2 = -i
            const float n1 = (sn[r * 3 + 1] && i > 0) ? v1 : -v1;
            const float n2 = (sn[r * 3 + 2] && i > 0) ? v2 : -v2;
            P[r][255 + i] = __halves2half2(__float2half_rn(p0), __float2half_rn(p1));
            P[r][255 - i] = __halves2half2(__float2half_rn(n0), __float2half_rn(n1));
            S[r][255 + i] = p2;
            S[r][255 - i] = n2;
        }
    }
    __syncthreads();

    // ---- 2) compute: 8 outputs per thread, pixels quantized in-reg -------
    const int row = tileY * RT + tid / 14;       // output row
    const int grp = tid % 14;
    const int c0  = grp * 8;
    const float* xp = x + (size_t)bc * (HH * WW);

    float acc[8];
    #pragma unroll
    for (int j = 0; j < 8; ++j) acc[j] = 0.0f;

    #pragma unroll
    for (int r = 0; r < 3; ++r) {
        const int py = row + r - 1;              // input row for kernel row r
        float p[10];                             // pixels c0-1 .. c0+8
        if (py >= 0 && py < HH) {
            const float* rp = xp + py * WW + c0;
            const float4 A  = *(const float4*)rp;
            const float4 Bv = *(const float4*)(rp + 4);
            p[0] = (grp > 0)  ? rp[-1] : 0.0f;   // left halo / zero pad
            p[1] = A.x;  p[2] = A.y;  p[3] = A.z;  p[4] = A.w;
            p[5] = Bv.x; p[6] = Bv.y; p[7] = Bv.z; p[8] = Bv.w;
            p[9] = (grp < 13) ? rp[8] : 0.0f;    // right halo / zero pad
        } else {
            #pragma unroll
            for (int j = 0; j < 10; ++j) p[j] = 0.0f;
        }
        int idx[10];
        #pragma unroll
        for (int j = 0; j < 10; ++j) {
            idx[j] = (int)fminf(fmaxf(rintf(p[j]), -255.0f), 255.0f) + 255;
        }
        // gathers: 9 pair-words + 8 singles = 17 b32 per row-visit
        __half2 g[9];
        #pragma unroll
        for (int j = 0; j < 9; ++j) g[j] = P[r][idx[j]];
        float s[8];
        #pragma unroll
        for (int j = 0; j < 8; ++j) s[j] = S[r][idx[j + 2]];
        // out[c] += tap0*px[c-1] + tap1*px[c] + tap2*px[c+1] (signed-LUT form)
        #pragma unroll
        for (int j = 0; j < 8; ++j) {
            acc[j] += __low2float(g[j]) + __high2float(g[j + 1]) + s[j];
        }
    }

    float4 o0, o1;
    o0.x = acc[0] * 0.001f; o0.y = acc[1] * 0.001f;
    o0.z = acc[2] * 0.001f; o0.w = acc[3] * 0.001f;
    o1.x = acc[4] * 0.001f; o1.y = acc[5] * 0.001f;
    o1.z = acc[6] * 0.001f; o1.w = acc[7] * 0.001f;
    float* od = out + (size_t)bc * (HH * WW) + row * WW + c0;
    *(float4*)od       = o0;
    *(float4*)(od + 4) = o1;
}

extern "C" void kernel_launch(void* const* d_in, const int* in_sizes, int n_in,
                              void* d_out, int out_size, void* d_ws, size_t ws_size,
                              hipStream_t stream) {
    const float* x   = (const float*)d_in[0];
    const float* w   = (const float*)d_in[1];
    const float* lut = (const float*)d_in[2];
    float* out = (float*)d_out;
    (void)in_sizes; (void)n_in; (void)out_size; (void)d_ws; (void)ws_size;

    const int grid = BB * CC * TILES_Y;          // 8*128*7 = 7168 blocks
    approx_dconv_kernel<<<grid, NTH, 0, stream>>>(x, w, lut, out);
}

// Round 5
// 116.904 us; speedup vs baseline: 1.0831x; 1.0204x over previous
//
#include <hip/hip_runtime.h>
#include <hip/hip_fp16.h>

// Problem constants (match reference)
#define BB 8
#define CC 128
#define HH 112
#define WW 112
#define NTH 224            // 16 row-groups x 14 col-groups
#define RG 7               // output rows per thread (16*7 = 112 = full plane)

// LUT depthwise 3x3, stride 1, pad 1:
//   t1 = clip(round(w*1000)), t2 = clip(round(x_pad)), both [-255,255]
//   out = sum_taps sign(t1,t2)*lut[|t1|,|t2|] / 1000 (sign=+1 iff strictly same sign)
//
// R5 (issue-bound per R4 post-mortem): minimize instructions per output.
//  - One block per (b,c) plane; thread = 7 rows x 8 cols. Rolling 3-row index
//    buffer: each input row quantized ONCE, reused by 3 kernel rows.
//  - Indices stored as pre-scaled byte offsets; P (half2) and S (float)
//    entries are both 4B so one offset serves all 6 tables (ds_read base
//    folds into the immediate) -> ~zero addressing VALU per gather.
//  - /1000 folded into fmaf(tap, 0.001f, acc): fma(fpext(f16),c,f32) selects
//    v_fma_mix_f32 (1 instr per fp16 contrib instead of cvt+add).
__global__ __launch_bounds__(NTH, 4)
void approx_dconv_kernel(const float* __restrict__ x,
                         const float* __restrict__ w,
                         const float* __restrict__ lut,
                         float* __restrict__ out) {
    __shared__ __half2 P[3][512];   // (tap k0, tap k1) per kernel row r; idx = t2+255
    __shared__ float   S[3][512];   // tap k2 per kernel row r

    const int tid = threadIdx.x;
    const int bc  = blockIdx.x;     // b*CC + c
    const int c   = bc % CC;

    // ---- 1) build signed per-tap tables (mirror fill) --------------------
    const float* wc = w + c * 9;
    int  i1[9];
    bool sp[9], sn[9];
    #pragma unroll
    for (int k = 0; k < 9; ++k) {
        float t1 = rintf(wc[k] * 1000.0f);
        t1 = fminf(fmaxf(t1, -255.0f), 255.0f);
        i1[k] = (int)fabsf(t1);
        sp[k] = (t1 > 0.0f);
        sn[k] = (t1 < 0.0f);
    }
    for (int i = tid; i < 256; i += NTH) {       // i == |t2|
        #pragma unroll
        for (int r = 0; r < 3; ++r) {
            const float v0 = lut[i1[r * 3 + 0] * 256 + i];
            const float v1 = lut[i1[r * 3 + 1] * 256 + i];
            const float v2 = lut[i1[r * 3 + 2] * 256 + i];
            const float p0 = (sp[r * 3 + 0] && i > 0) ? v0 : -v0;  // t2 = +i
            const float p1 = (sp[r * 3 + 1] && i > 0) ? v1 : -v1;
            const float p2 = (sp[r * 3 + 2] && i > 0) ? v2 : -v2;
            const float n0 = (sn[r * 3 + 0] && i > 0) ? v0 : -v0;  // t2 = -i
            const float n1 = (sn[r * 3 + 1] && i > 0) ? v1 : -v1;
            const float n2 = (sn[r * 3 + 2] && i > 0) ? v2 : -v2;
            P[r][255 + i] = __halves2half2(__float2half_rn(p0), __float2half_rn(p1));
            P[r][255 - i] = __halves2half2(__float2half_rn(n0), __float2half_rn(n1));
            S[r][255 + i] = p2;
            S[r][255 - i] = n2;
        }
    }
    __syncthreads();

    // ---- 2) compute: rolling 3-row offsets, 8 outputs per row-iter -------
    const int rg = tid / 14;                     // 0..15
    const int cg = tid % 14;                     // 0..13
    const int y0 = rg * RG;
    const int c0 = cg * 8;
    const float* xp = x + (size_t)bc * (HH * WW);
    float* op = out + (size_t)bc * (HH * WW);

    int off[3][10];                              // byte offsets (idx*4), px c0-1..c0+8

    auto loadq = [&](int py, int* o) {
        if (py >= 0 && py < HH) {
            const float* rp = xp + py * WW + c0;
            float p[10];
            p[0] = (cg > 0) ? rp[-1] : 0.0f;     // left halo / zero pad
            const float4 A  = *(const float4*)rp;
            const float4 Bv = *(const float4*)(rp + 4);
            p[1] = A.x;  p[2] = A.y;  p[3] = A.z;  p[4] = A.w;
            p[5] = Bv.x; p[6] = Bv.y; p[7] = Bv.z; p[8] = Bv.w;
            p[9] = (cg < 13) ? rp[8] : 0.0f;     // right halo / zero pad
            #pragma unroll
            for (int j = 0; j < 10; ++j) {
                int q = (int)rintf(p[j]);
                q = q < -255 ? -255 : (q > 255 ? 255 : q);   // med3
                o[j] = (q + 255) << 2;
            }
        } else {
            #pragma unroll
            for (int j = 0; j < 10; ++j) o[j] = 255 << 2;
        }
    };

    loadq(y0 - 1, off[0]);
    loadq(y0,     off[1]);
    const float cmul = 0.001f;

    #pragma unroll
    for (int y = 0; y < RG; ++y) {
        loadq(y0 + y + 1, off[(y + 2) % 3]);     // new input row
        float acc[8];
        #pragma unroll
        for (int j = 0; j < 8; ++j) acc[j] = 0.0f;
        #pragma unroll
        for (int r = 0; r < 3; ++r) {            // kernel row r uses input row y0+y+r-1
            const int* o = off[(y + r) % 3];
            const char* Pb = (const char*)&P[r][0];
            const char* Sb = (const char*)&S[r][0];
            __half2 g[9];
            #pragma unroll
            for (int j = 0; j < 9; ++j) g[j] = *(const __half2*)(Pb + o[j]);
            float s[8];
            #pragma unroll
            for (int j = 0; j < 8; ++j) s[j] = *(const float*)(Sb + o[j + 2]);
            #pragma unroll
            for (int j = 0; j < 8; ++j) {
                acc[j] = fmaf(__low2float(g[j]),      cmul, acc[j]);  // k0 @ px c-1
                acc[j] = fmaf(__high2float(g[j + 1]), cmul, acc[j]);  // k1 @ px c
                acc[j] = fmaf(s[j],                   cmul, acc[j]);  // k2 @ px c+1
            }
        }
        float4 o0 = make_float4(acc[0], acc[1], acc[2], acc[3]);
        float4 o1 = make_float4(acc[4], acc[5], acc[6], acc[7]);
        float* od = op + (y0 + y) * WW + c0;
        *(float4*)od       = o0;
        *(float4*)(od + 4) = o1;
    }
}

extern "C" void kernel_launch(void* const* d_in, const int* in_sizes, int n_in,
                              void* d_out, int out_size, void* d_ws, size_t ws_size,
                              hipStream_t stream) {
    const float* x   = (const float*)d_in[0];
    const float* w   = (const float*)d_in[1];
    const float* lut = (const float*)d_in[2];
    float* out = (float*)d_out;
    (void)in_sizes; (void)n_in; (void)out_size; (void)d_ws; (void)ws_size;

    const int grid = BB * CC;                    // 1024 blocks: one (b,c) plane each
    approx_dconv_kernel<<<grid, NTH, 0, stream>>>(x, w, lut, out);
}